// Round 1
// baseline (12965.248 us; speedup 1.0000x reference)
//
#include <hip/hip_runtime.h>
#include <hip/hip_bf16.h>

typedef __attribute__((ext_vector_type(8))) short s16x8;
typedef __attribute__((ext_vector_type(4))) float f32x4;

__device__ inline unsigned short f2bf(float f) {
  unsigned u = __builtin_bit_cast(unsigned, f);
  unsigned r = (u + 0x7FFFu + ((u >> 16) & 1u)) >> 16;  // RTNE
  return (unsigned short)r;
}
__device__ inline float bf2f(short v) {
  return __builtin_bit_cast(float, ((unsigned)(unsigned short)v) << 16);
}
__device__ inline float sigf(float x) { return 1.f / (1.f + __expf(-x)); }
__device__ inline float tanhf_(float x) { float e = __expf(2.f * x); return 1.f - 2.f / (e + 1.f); }

// ---------------------------------------------------------------- conv/pad
__global__ void conv_pad(const float* __restrict__ src, unsigned short* __restrict__ dst,
                         int rows, int scols, int dcols) {
  int i = blockIdx.x * 256 + threadIdx.x;
  if (i >= rows * dcols) return;
  int r = i / dcols, cc = i % dcols;
  dst[i] = (cc < scols) ? f2bf(src[(size_t)r * scols + cc]) : (unsigned short)0;
}

// ---------------------------------------------------------------- GEMM C = A @ B^T + bias
// A: [M,K] (f32 or bf16), B: [N,K] f32 (weights), C: [M,N] (f32 or bf16)
#define BM 128
#define BN 128
#define BKK 32

template<int A_BF16, int C_BF16>
__global__ __launch_bounds__(256) void gemm_bt(const void* __restrict__ Av,
    const float* __restrict__ B, const float* __restrict__ bias,
    void* __restrict__ Cv, int M, int N, int K) {
  __shared__ short sA[BM * BKK];
  __shared__ short sB[BN * BKK];
  const int tid = threadIdx.x;
  const int l = tid & 63;
  const int wid = tid >> 6;
  const int wr = wid >> 1, wc = wid & 1;
  const int lr = l & 15, kg = l >> 4;
  const int bn = blockIdx.x, bm = blockIdx.y;   // bn fastest -> A-tile L2 reuse
  const int arow = tid >> 1;
  const int acol = (tid & 1) * 16;

  f32x4 acc[4][4];
#pragma unroll
  for (int i = 0; i < 4; ++i)
#pragma unroll
    for (int j = 0; j < 4; ++j) acc[i][j] = (f32x4){0.f, 0.f, 0.f, 0.f};

  for (int kt = 0; kt < K; kt += BKK) {
    __syncthreads();
    if (A_BF16) {
      const unsigned short* src = (const unsigned short*)Av + (size_t)(bm * BM + arow) * K + kt + acol;
      *(s16x8*)&sA[arow * BKK + acol] = *(const s16x8*)src;
      *(s16x8*)&sA[arow * BKK + acol + 8] = *(const s16x8*)(src + 8);
    } else {
      const float* src = (const float*)Av + (size_t)(bm * BM + arow) * K + kt + acol;
      s16x8 v0, v1;
#pragma unroll
      for (int e = 0; e < 8; ++e) { v0[e] = (short)f2bf(src[e]); v1[e] = (short)f2bf(src[8 + e]); }
      *(s16x8*)&sA[arow * BKK + acol] = v0;
      *(s16x8*)&sA[arow * BKK + acol + 8] = v1;
    }
    {
      const float* src = B + (size_t)(bn * BN + arow) * K + kt + acol;
      s16x8 v0, v1;
#pragma unroll
      for (int e = 0; e < 8; ++e) { v0[e] = (short)f2bf(src[e]); v1[e] = (short)f2bf(src[8 + e]); }
      *(s16x8*)&sB[arow * BKK + acol] = v0;
      *(s16x8*)&sB[arow * BKK + acol + 8] = v1;
    }
    __syncthreads();
    s16x8 af[4], bfr[4];
#pragma unroll
    for (int mi = 0; mi < 4; ++mi)
      af[mi] = *(const s16x8*)&sA[(wr * 64 + mi * 16 + lr) * BKK + kg * 8];
#pragma unroll
    for (int ni = 0; ni < 4; ++ni)
      bfr[ni] = *(const s16x8*)&sB[(wc * 64 + ni * 16 + lr) * BKK + kg * 8];
#pragma unroll
    for (int mi = 0; mi < 4; ++mi)
#pragma unroll
      for (int ni = 0; ni < 4; ++ni)
        acc[mi][ni] = __builtin_amdgcn_mfma_f32_16x16x32_bf16(af[mi], bfr[ni], acc[mi][ni], 0, 0, 0);
  }
  const int r0 = bm * BM + wr * 64;
  const int c0 = bn * BN + wc * 64;
#pragma unroll
  for (int mi = 0; mi < 4; ++mi)
#pragma unroll
    for (int ni = 0; ni < 4; ++ni) {
      const int col = c0 + ni * 16 + lr;
      const float bv = bias[col];
#pragma unroll
      for (int e = 0; e < 4; ++e) {
        const int row = r0 + mi * 16 + kg * 4 + e;
        const float v = acc[mi][ni][e] + bv;
        if (C_BF16) ((unsigned short*)Cv)[(size_t)row * N + col] = f2bf(v);
        else        ((float*)Cv)[(size_t)row * N + col] = v;
      }
    }
}

// ---------------------------------------------------------------- LSTM scan (one layer)
// pre: [T][128][512] f32 (x@Wih.T + b precomputed), Whh: [512][128] f32, hs out: [T][128][128] bf16.
// 8 WGs x 512 threads; WG owns 16 batch rows for the whole scan. Whh fragments hoisted to VGPRs.
__global__ __launch_bounds__(512) void lstm_scan(const float* __restrict__ pre,
    const float* __restrict__ Whh, unsigned short* __restrict__ hs, int T) {
  __shared__ unsigned short hb[2][2048];   // double-buffered h tile [16][128] bf16, XOR-swizzled
  const int tid = threadIdx.x;
  const int l = tid & 63, w = tid >> 6;
  const int wg = blockIdx.x;
  const int lr = l & 15, kg = l >> 4;
  const int col = w * 16 + lr;     // h-column this thread updates (and B-frag col)
  const int rbase = kg * 4;        // local batch rows rbase..rbase+3 (C-frag rows)

  // hoist Whh B-fragments: wf[gate][kslice], loop-invariant
  s16x8 wf[4][4];
#pragma unroll
  for (int gi = 0; gi < 4; ++gi)
#pragma unroll
    for (int kk = 0; kk < 4; ++kk) {
      const float* p = Whh + (size_t)(gi * 128 + col) * 128 + kk * 32 + kg * 8;
#pragma unroll
      for (int e = 0; e < 8; ++e) wf[gi][kk][e] = (short)f2bf(p[e]);
    }
  for (int i = tid; i < 4096; i += 512) ((unsigned short*)hb)[i] = 0;
  float c[4] = {0.f, 0.f, 0.f, 0.f};

  const float* pbase = pre + ((size_t)(wg * 16 + rbase)) * 512 + col;
  float pf[16];
#pragma unroll
  for (int gi = 0; gi < 4; ++gi)
#pragma unroll
    for (int e = 0; e < 4; ++e) pf[gi * 4 + e] = pbase[e * 512 + gi * 128];
  __syncthreads();

  for (int t = 0; t < T; ++t) {
    const unsigned short* hc = hb[t & 1];
    unsigned short* hn = hb[(t & 1) ^ 1];
    // A-fragments of h (prev step) from swizzled LDS
    s16x8 a[4];
#pragma unroll
    for (int kk = 0; kk < 4; ++kk) {
      const int byt = lr * 256 + ((kk * 64 + kg * 16) ^ ((lr & 7) << 4));
      a[kk] = *(const s16x8*)((const char*)hc + byt);
    }
    f32x4 acc[4];
#pragma unroll
    for (int gi = 0; gi < 4; ++gi)
      acc[gi] = (f32x4){pf[gi * 4], pf[gi * 4 + 1], pf[gi * 4 + 2], pf[gi * 4 + 3]};
    // prefetch pre[t+1] under compute
    float pfn[16];
    if (t + 1 < T) {
      const float* pb2 = pbase + (size_t)(t + 1) * 65536;
#pragma unroll
      for (int gi = 0; gi < 4; ++gi)
#pragma unroll
        for (int e = 0; e < 4; ++e) pfn[gi * 4 + e] = pb2[e * 512 + gi * 128];
    } else {
#pragma unroll
      for (int i2 = 0; i2 < 16; ++i2) pfn[i2] = 0.f;
    }
#pragma unroll
    for (int kk = 0; kk < 4; ++kk)
#pragma unroll
      for (int gi = 0; gi < 4; ++gi)
        acc[gi] = __builtin_amdgcn_mfma_f32_16x16x32_bf16(a[kk], wf[gi][kk], acc[gi], 0, 0, 0);
    // gates: PyTorch order i,f,g,o
#pragma unroll
    for (int e = 0; e < 4; ++e) {
      float gi_ = sigf(acc[0][e]);
      float gf  = sigf(acc[1][e]);
      float gg  = tanhf_(acc[2][e]);
      float go  = sigf(acc[3][e]);
      c[e] = gf * c[e] + gi_ * gg;
      float h = go * tanhf_(c[e]);
      unsigned short hu = f2bf(h);
      int row = rbase + e;
      int byt = row * 256 + ((col * 2) ^ ((row & 7) << 4));
      *(unsigned short*)((char*)hn + byt) = hu;
      hs[((size_t)t * 128 + wg * 16 + row) * 128 + col] = hu;
    }
#pragma unroll
    for (int i2 = 0; i2 < 16; ++i2) pf[i2] = pfn[i2];
    __syncthreads();
  }
}

// ---------------------------------------------------------------- decoder: 128 independent WGs, one batch row each
__global__ __launch_bounds__(512) void decoder_k(
    const unsigned short* __restrict__ kb, const unsigned short* __restrict__ vb,
    const unsigned short* __restrict__ W0, const unsigned short* __restrict__ Wh0,
    const unsigned short* __restrict__ Wi1, const unsigned short* __restrict__ Wh1,
    const unsigned short* __restrict__ Wqm, const unsigned short* __restrict__ Wom,
    const float* __restrict__ b0, const float* __restrict__ b1,
    const float* __restrict__ bq, const float* __restrict__ bo,
    const float* __restrict__ linW, const float* __restrict__ linb,
    float* __restrict__ out) {
  const int b = blockIdx.x;
  const int tid = threadIdx.x;
  const int l = tid & 63, wv = tid >> 6;
  __shared__ float xin[136];                       // [0..3]=y, [4..131]=ct, pad->0
  __shared__ float h0s[128], c0s[128], h1s[128], c1s[128];
  __shared__ float gb[512];
  __shared__ float qs[128];
  __shared__ float sc[4][512];
  __shared__ float red[32];
  __shared__ float mx4[4], is4[4];
  __shared__ float avp[16][32];
  __shared__ float ctv[128];
  __shared__ float ctl[128];
  for (int i = tid; i < 136; i += 512) xin[i] = 0.f;
  if (tid < 128) { h0s[tid] = 0.f; c0s[tid] = 0.f; h1s[tid] = 0.f; c1s[tid] = 0.f; }
  __syncthreads();

  for (int s = 0; s < 64; ++s) {
    // layer-0 gates: g[tid] = b0 + Wih0.xin + Whh0.h0
    {
      float acc = b0[tid];
      const s16x8* wr = (const s16x8*)(W0 + (size_t)tid * 136);
#pragma unroll
      for (int cc = 0; cc < 17; ++cc) {
        s16x8 wvv = wr[cc];
#pragma unroll
        for (int e = 0; e < 8; ++e) acc += xin[cc * 8 + e] * bf2f(wvv[e]);
      }
      const s16x8* w2 = (const s16x8*)(Wh0 + (size_t)tid * 128);
#pragma unroll
      for (int cc = 0; cc < 16; ++cc) {
        s16x8 wvv = w2[cc];
#pragma unroll
        for (int e = 0; e < 8; ++e) acc += h0s[cc * 8 + e] * bf2f(wvv[e]);
      }
      gb[tid] = acc;
    }
    __syncthreads();
    if (tid < 128) {
      float c = sigf(gb[128 + tid]) * c0s[tid] + sigf(gb[tid]) * tanhf_(gb[256 + tid]);
      c0s[tid] = c;
      h0s[tid] = sigf(gb[384 + tid]) * tanhf_(c);
    }
    __syncthreads();
    // layer-1 gates
    {
      float acc = b1[tid];
      const s16x8* w1 = (const s16x8*)(Wi1 + (size_t)tid * 128);
      const s16x8* w2 = (const s16x8*)(Wh1 + (size_t)tid * 128);
#pragma unroll
      for (int cc = 0; cc < 16; ++cc) {
        s16x8 a_ = w1[cc], b_ = w2[cc];
#pragma unroll
        for (int e = 0; e < 8; ++e) acc += h0s[cc * 8 + e] * bf2f(a_[e]) + h1s[cc * 8 + e] * bf2f(b_[e]);
      }
      gb[tid] = acc;
    }
    __syncthreads();
    if (tid < 128) {
      float c = sigf(gb[128 + tid]) * c1s[tid] + sigf(gb[tid]) * tanhf_(gb[256 + tid]);
      c1s[tid] = c;
      h1s[tid] = sigf(gb[384 + tid]) * tanhf_(c);
    }
    __syncthreads();
    // q = Wq.h1 + bq
    if (tid < 128) {
      float acc = bq[tid];
      const s16x8* wq = (const s16x8*)(Wqm + (size_t)tid * 128);
#pragma unroll
      for (int cc = 0; cc < 16; ++cc) {
        s16x8 wvv = wq[cc];
#pragma unroll
        for (int e = 0; e < 8; ++e) acc += h1s[cc * 8 + e] * bf2f(wvv[e]);
      }
      qs[tid] = acc;
    }
    __syncthreads();
    // scores: thread tid handles t = tid, all 4 heads (k row contiguous 256B)
    {
      const s16x8* kr = (const s16x8*)(kb + ((size_t)tid * 128 + b) * 128);
      float s4[4] = {0.f, 0.f, 0.f, 0.f};
#pragma unroll
      for (int cc = 0; cc < 16; ++cc) {
        s16x8 kvv = kr[cc];
#pragma unroll
        for (int e = 0; e < 8; ++e) s4[cc >> 2] += qs[cc * 8 + e] * bf2f(kvv[e]);
      }
      const float scale = 0.1767766952966369f;  // 1/sqrt(32)
#pragma unroll
      for (int h = 0; h < 4; ++h) {
        s4[h] *= scale;
        sc[h][tid] = s4[h];
        float m = s4[h];
#pragma unroll
        for (int off = 32; off > 0; off >>= 1) m = fmaxf(m, __shfl_xor(m, off));
        if (l == 0) red[wv * 4 + h] = m;
      }
    }
    __syncthreads();
    if (tid < 4) {
      float m = red[tid];
#pragma unroll
      for (int w2 = 1; w2 < 8; ++w2) m = fmaxf(m, red[w2 * 4 + tid]);
      mx4[tid] = m;
    }
    __syncthreads();
    {
#pragma unroll
      for (int h = 0; h < 4; ++h) {
        float p = __expf(sc[h][tid] - mx4[h]);
        sc[h][tid] = p;
#pragma unroll
        for (int off = 32; off > 0; off >>= 1) p += __shfl_xor(p, off);
        if (l == 0) red[wv * 4 + h] = p;
      }
    }
    __syncthreads();
    if (tid < 4) {
      float sm = 0.f;
#pragma unroll
      for (int w2 = 0; w2 < 8; ++w2) sm += red[w2 * 4 + tid];
      is4[tid] = 1.f / sm;
    }
    __syncthreads();
    // AV: thread -> (h, t-chunk, d); 128-long partial sums
    {
      const int h = tid >> 7, rem = tid & 127, tc = rem >> 5, d = rem & 31;
      float acc = 0.f;
      const unsigned short* vp = vb + ((size_t)(tc * 128) * 128 + b) * 128 + h * 32 + d;
#pragma unroll 4
      for (int tt = 0; tt < 128; ++tt)
        acc += sc[h][tc * 128 + tt] * bf2f((short)vp[(size_t)tt * 16384]);
      avp[h * 4 + tc][d] = acc;
    }
    __syncthreads();
    if (tid < 128) {
      const int h = tid >> 5, d = tid & 31;
      ctv[tid] = (avp[h * 4 + 0][d] + avp[h * 4 + 1][d] + avp[h * 4 + 2][d] + avp[h * 4 + 3][d]) * is4[h];
    }
    __syncthreads();
    // ct = Wo.ctv + bo ; also next step's xin[4..]
    if (tid < 128) {
      float acc = bo[tid];
      const s16x8* wo = (const s16x8*)(Wom + (size_t)tid * 128);
#pragma unroll
      for (int cc = 0; cc < 16; ++cc) {
        s16x8 wvv = wo[cc];
#pragma unroll
        for (int e = 0; e < 8; ++e) acc += ctv[cc * 8 + e] * bf2f(wvv[e]);
      }
      ctl[tid] = acc;
      xin[4 + tid] = acc;
    }
    __syncthreads();
    // y = [h1, ct] @ lin_W.T + lin_b  (4 outputs, one wave each)
    if (tid < 256) {
      const int o = tid >> 6, kk = tid & 63;
      const float* lw = linW + o * 256;
      float part = h1s[kk] * lw[kk] + h1s[kk + 64] * lw[kk + 64]
                 + ctl[kk] * lw[128 + kk] + ctl[kk + 64] * lw[192 + kk];
#pragma unroll
      for (int off = 32; off > 0; off >>= 1) part += __shfl_xor(part, off);
      if (kk == 0) {
        float yv = part + linb[o];
        out[((size_t)s * 128 + b) * 4 + o] = yv;
        xin[o] = yv;
      }
    }
    __syncthreads();
  }
}

// ---------------------------------------------------------------- launch
extern "C" void kernel_launch(void* const* d_in, const int* in_sizes, int n_in,
                              void* d_out, int out_size, void* d_ws, size_t ws_size,
                              hipStream_t stream) {
  (void)in_sizes; (void)n_in; (void)out_size; (void)ws_size;
  const float* x     = (const float*)d_in[0];
  const float* eWih0 = (const float*)d_in[1];
  const float* eWhh0 = (const float*)d_in[2];
  const float* eb0   = (const float*)d_in[3];
  const float* eWih1 = (const float*)d_in[4];
  const float* eWhh1 = (const float*)d_in[5];
  const float* eb1   = (const float*)d_in[6];
  const float* dWih0 = (const float*)d_in[7];
  const float* dWhh0 = (const float*)d_in[8];
  const float* db0   = (const float*)d_in[9];
  const float* dWih1 = (const float*)d_in[10];
  const float* dWhh1 = (const float*)d_in[11];
  const float* db1   = (const float*)d_in[12];
  const float* Wq    = (const float*)d_in[13];
  const float* bq    = (const float*)d_in[14];
  const float* Wk    = (const float*)d_in[15];
  const float* bk    = (const float*)d_in[16];
  const float* Wv    = (const float*)d_in[17];
  const float* bv    = (const float*)d_in[18];
  const float* Wo    = (const float*)d_in[19];
  const float* bo    = (const float*)d_in[20];
  const float* linW  = (const float*)d_in[21];
  const float* linb  = (const float*)d_in[22];

  char* w = (char*)d_ws;
  float* pre = (float*)w;
  size_t off = (size_t)65536 * 512 * 4;                                   // 128 MB (reused by both layers)
  unsigned short* hs0  = (unsigned short*)(w + off); off += (size_t)65536 * 128 * 2;
  unsigned short* enc  = (unsigned short*)(w + off); off += (size_t)65536 * 128 * 2;
  unsigned short* kbuf = (unsigned short*)(w + off); off += (size_t)65536 * 128 * 2;
  unsigned short* vbuf = (unsigned short*)(w + off); off += (size_t)65536 * 128 * 2;
  unsigned short* W0p  = (unsigned short*)(w + off); off += 512 * 136 * 2;
  unsigned short* Wh0d = (unsigned short*)(w + off); off += 512 * 128 * 2;
  unsigned short* Wi1d = (unsigned short*)(w + off); off += 512 * 128 * 2;
  unsigned short* Wh1d = (unsigned short*)(w + off); off += 512 * 128 * 2;
  unsigned short* Wqd  = (unsigned short*)(w + off); off += 128 * 128 * 2;
  unsigned short* Wod  = (unsigned short*)(w + off); off += 128 * 128 * 2;

  conv_pad<<<(512 * 136 + 255) / 256, 256, 0, stream>>>(dWih0, W0p, 512, 132, 136);
  conv_pad<<<(512 * 128 + 255) / 256, 256, 0, stream>>>(dWhh0, Wh0d, 512, 128, 128);
  conv_pad<<<(512 * 128 + 255) / 256, 256, 0, stream>>>(dWih1, Wi1d, 512, 128, 128);
  conv_pad<<<(512 * 128 + 255) / 256, 256, 0, stream>>>(dWhh1, Wh1d, 512, 128, 128);
  conv_pad<<<(128 * 128 + 255) / 256, 256, 0, stream>>>(Wq, Wqd, 128, 128, 128);
  conv_pad<<<(128 * 128 + 255) / 256, 256, 0, stream>>>(Wo, Wod, 128, 128, 128);

  // encoder
  gemm_bt<0, 0><<<dim3(4, 512), 256, 0, stream>>>((const void*)x, eWih0, eb0, (void*)pre, 65536, 512, 1024);
  lstm_scan<<<8, 512, 0, stream>>>(pre, eWhh0, hs0, 512);
  gemm_bt<1, 0><<<dim3(4, 512), 256, 0, stream>>>((const void*)hs0, eWih1, eb1, (void*)pre, 65536, 512, 128);
  lstm_scan<<<8, 512, 0, stream>>>(pre, eWhh1, enc, 512);
  // K/V projections
  gemm_bt<1, 1><<<dim3(1, 512), 256, 0, stream>>>((const void*)enc, Wk, bk, (void*)kbuf, 65536, 128, 128);
  gemm_bt<1, 1><<<dim3(1, 512), 256, 0, stream>>>((const void*)enc, Wv, bv, (void*)vbuf, 65536, 128, 128);
  // decoder
  decoder_k<<<128, 512, 0, stream>>>(kbuf, vbuf, W0p, Wh0d, Wi1d, Wh1d, Wqd, Wod,
                                     db0, db1, bq, bo, linW, linb, (float*)d_out);
}